// Round 4
// baseline (355.071 us; speedup 1.0000x reference)
//
#include <hip/hip_runtime.h>
#include <cmath>

// FFTConv via chunked diagonal SSM + MFMA.
//
// y[n] = tanh( sum_{d>=0} k_d u[n-d] (circular) + D*u[n] ),  k_d = Re sum_p bc_p A_p^d.
// Chunk n = c*128 + r (nc=64 chunks):
//   y[c,r] = sum_j T'[r][j] u[c*128+j]  +  Re sum_p bc_p A_p^{r+1} sB_p[c]
//   T'[r][j] = k_{r-j} (j<=r) + D*(j==r)
//   sB[c+1]  = A^128 sB[c] + S_in[c],  S_in[c] = sum_j A^{127-j} u[c*128+j]
//
// R4: pipeline buffer moved from VGPRs (R2/R3 spilled: WRITE_SIZE +35/+120 MB)
// to LDS via global_load_lds (width=16, zero reg cost):
//   - u staged as f32 into a swizzled 32 KB strip by DMA; GEMM1 converts
//     fragments f32->f16 on the fly and writes them back to a 16 KB fp16 tile
//     (each wave owns 2 s-slices); strip is then dead -> DMA target for seq+1,
//     issued right after the post-GEMM1 barrier, covered by scan+GEMM2.
//   - scan is in-place (no er/ei arrays): warm-up taps -> sr/si, barrier,
//     then read-write own rows.  8-tap circular warm start (|A^128|^8<=3.4e-5).
//   - in-seq barriers are lgkm-only raw barriers (do NOT drain vmcnt => DMA
//     stays in flight); one full __syncthreads per seq end.
// NSEQ=4 seqs/block, grid 1024 = exactly 2 rounds at 2 blocks/CU (LDS 64 KB).
// blk = bbg*256 + h keeps all blocks of one h on one XCD (A2[h] L2-local).

typedef _Float16 half8 __attribute__((ext_vector_type(8)));
typedef _Float16 half4v __attribute__((ext_vector_type(4)));
typedef _Float16 half2v __attribute__((ext_vector_type(2)));
typedef float floatx16 __attribute__((ext_vector_type(16)));

#define NC 64
#define CM 128
#define NSEQ 4
#define A2_BYTES ((size_t)256 * 128 * 256 * 2)
#define W_BYTES  ((size_t)128 * 128 * 2)
#define AM_OFF   (A2_BYTES + W_BYTES)

// fp16 tile swizzle (half units): 16B chunk index XORed with row
#define SWH(r, c) ((((r) << 7)) | ((c) ^ (((r) & 15) << 3)))
// f32 tile swizzle (float units): 32 16B-chunks/row, physical = logical ^ (c&31)
#define SWF(c, q4) (((c) << 7) | ((((q4) ^ ((c) & 31))) << 2))

#define BAR_LGKM() do { \
    asm volatile("s_waitcnt lgkmcnt(0)" ::: "memory"); \
    __builtin_amdgcn_sched_barrier(0); \
    __builtin_amdgcn_s_barrier(); \
} while (0)

__device__ __forceinline__ float fast_tanh(float x) {
    float e2 = __expf(2.0f * x);
    return 1.0f - 2.0f / (e2 + 1.0f);   // exact +/-1 at saturation, no NaN
}

__device__ __forceinline__ void dma16(const void* g, void* l) {
    __builtin_amdgcn_global_load_lds(
        (const __attribute__((address_space(1))) void*)g,
        (__attribute__((address_space(3))) void*)l, 16, 0, 0);
}

__global__ void fftconv_prep(const float* __restrict__ A_re, const float* __restrict__ A_im,
                             const float* __restrict__ BC_re, const float* __restrict__ BC_im,
                             const float* __restrict__ Dv, char* __restrict__ ws) {
    __shared__ float rr[64], th[64], br[64], bi[64];
    __shared__ float kk[CM];
    const int h = blockIdx.x, tid = threadIdx.x;
    if (tid < 64) {
        float x = A_re[tid], y = A_im[tid];
        rr[tid] = log2f(sqrtf(x * x + y * y));   // log2|A|
        th[tid] = atan2f(y, x);                  // arg(A)
        br[tid] = BC_re[h * 64 + tid];
        bi[tid] = BC_im[h * 64 + tid];
    }
    __syncthreads();
    if (tid < CM) {   // kernel taps k_d, d = 0..127
        float d = (float)tid, s = 0.f;
        for (int p = 0; p < 64; ++p) {
            float mag = exp2f(d * rr[p]);
            float ang = d * th[p];
            s += mag * (br[p] * cosf(ang) - bi[p] * sinf(ang));
        }
        kk[tid] = s;
    }
    __syncthreads();
    _Float16* A2 = (_Float16*)ws + (size_t)h * 128 * 256;
    const float Dh = Dv[h];
    // G part: col index = cidx = 2p+im (re/im interleaved to match sB layout)
    for (int idx = tid; idx < 128 * 128; idx += 256) {
        int r = idx >> 7, pc = idx & 127, p = pc & 63;
        float e = (float)(r + 1);
        float mag = exp2f(e * rr[p]);
        float ang = e * th[p];
        float cr = mag * cosf(ang), ci = mag * sinf(ang);
        float val = (pc < 64) ? (br[p] * cr - bi[p] * ci) : -(br[p] * ci + bi[p] * cr);
        int cn = ((pc & 63) << 1) | (pc >> 6);
        A2[r * 256 + cn] = (_Float16)val;
    }
    // T' part: A2[r][128+j] = k_{r-j} (j<=r) + D*(j==r)
    for (int idx = tid; idx < 128 * 128; idx += 256) {
        int r = idx >> 7, j = idx & 127;
        float v = (j <= r) ? kk[r - j] : 0.f;
        if (j == r) v += Dh;
        A2[r * 256 + CM + j] = (_Float16)v;
    }
    if (h == 0) {
        _Float16* W = (_Float16*)(ws + A2_BYTES);   // row index = cidx = 2p+im
        for (int idx = tid; idx < 128 * 128; idx += 256) {
            int pc = idx >> 7, j = idx & 127, p = pc & 63;
            float e = (float)(127 - j);
            float mag = exp2f(e * rr[p]);
            float ang = e * th[p];
            float v = (pc < 64) ? mag * cosf(ang) : mag * sinf(ang);
            int rn = ((pc & 63) << 1) | (pc >> 6);
            W[rn * 128 + j] = (_Float16)v;
        }
        if (tid < 64) {   // A^128 fp32 for the scan
            float mag = exp2f(128.f * rr[tid]);
            float ang = 128.f * th[tid];
            float* aM = (float*)(ws + AM_OFF);
            aM[tid] = mag * cosf(ang);
            aM[64 + tid] = mag * sinf(ang);
        }
    }
}

__global__ __launch_bounds__(256, 2)
void fftconv_main(const float* __restrict__ u, const char* __restrict__ ws,
                  float* __restrict__ out) {
    __shared__ __align__(16) float    u32t[NC * CM];   // 32 KB f32 DMA strip (swizzled)
    __shared__ __align__(16) _Float16 u16t[NC * CM];   // 16 KB fp16 u tile
    __shared__ __align__(16) _Float16 S16[NC * CM];    // 16 KB S_in / sB

    const int tid = threadIdx.x;
    const int lane = tid & 63;
    const int wv = tid >> 6;
    const int h = blockIdx.x & 255;       // blk%8 == h%8 -> one XCD per h
    const int bbg = blockIdx.x >> 8;      // 0..3 -> bb quad

    const int mrow = (wv << 5) + (lane & 31);      // output row (cidx / r)
    const int kh = (lane >> 5) << 3;               // k-offset within frag
    const int ncol = lane & 31;                    // output column (c)

    const _Float16* Wg = (const _Float16*)(ws + A2_BYTES) + (size_t)mrow * CM + kh;
    const _Float16* Ag = (const _Float16*)ws + ((size_t)h * CM + mrow) * 256 + kh;
    const float* aM = (const float*)(ws + AM_OFF);
    const float amr = aM[lane], ami = aM[64 + lane];

    // fragment preloads (L2-local tables), once per block
    half8 wf[8], tf[8], gf[8];
#pragma unroll
    for (int s = 0; s < 8; ++s) wf[s] = *(const half8*)(Wg + (s << 4));
#pragma unroll
    for (int s = 0; s < 8; ++s) tf[s] = *(const half8*)(Ag + CM + (s << 4));
#pragma unroll
    for (int s = 0; s < 8; ++s) gf[s] = *(const half8*)(Ag + (s << 4));

    // DMA seq0 -> f32 strip (8 wave-issues x 1 KB; LDS dest wave-uniform,
    // global src carries the inverse chunk swizzle)
    {
        const float* ub = u + ((size_t)((bbg * NSEQ + 0) * 256) + h) * 8192;
#pragma unroll
        for (int q = 0; q < 8; ++q) {
            int c = (wv << 4) + (q << 1) + (lane >> 5);
            int q4 = (lane & 31) ^ (c & 31);
            dma16(ub + (c << 7) + (q4 << 2), u32t + (((wv << 4) + (q << 1)) << 7));
        }
    }
    __syncthreads();   // drains DMA0 + fragment loads

#pragma unroll 1
    for (int sq = 0; sq < NSEQ; ++sq) {
        // ---- GEMM1: S_in = W * u  (f32 frags, cvt on the fly, u16 writeback) ----
        {
            floatx16 a0 = {}; floatx16 a1 = {};
#pragma unroll
            for (int s = 0; s < 8; ++s) {
                int k0 = (s << 4) + kh;
                int q4 = k0 >> 2;   // even
                float4 xa = *(const float4*)&u32t[SWF(ncol, q4)];
                float4 xb = *(const float4*)&u32t[SWF(ncol, q4 + 1)];
                float4 ya = *(const float4*)&u32t[SWF(ncol + 32, q4)];
                float4 yb2 = *(const float4*)&u32t[SWF(ncol + 32, q4 + 1)];
                half8 b0 = { (_Float16)xa.x, (_Float16)xa.y, (_Float16)xa.z, (_Float16)xa.w,
                             (_Float16)xb.x, (_Float16)xb.y, (_Float16)xb.z, (_Float16)xb.w };
                half8 b1 = { (_Float16)ya.x, (_Float16)ya.y, (_Float16)ya.z, (_Float16)ya.w,
                             (_Float16)yb2.x, (_Float16)yb2.y, (_Float16)yb2.z, (_Float16)yb2.w };
                if ((s >> 1) == wv) {   // each wave persists its 2 s-slices as fp16
                    *(half8*)&u16t[SWH(ncol, k0)] = b0;
                    *(half8*)&u16t[SWH(ncol + 32, k0)] = b1;
                }
                a0 = __builtin_amdgcn_mfma_f32_32x32x16_f16(wf[s], b0, a0, 0, 0, 0);
                a1 = __builtin_amdgcn_mfma_f32_32x32x16_f16(wf[s], b1, a1, 0, 0, 0);
            }
            const int pc0 = (wv << 5) + ((lane >> 5) << 2);
#pragma unroll
            for (int g = 0; g < 4; ++g) {
                half4v h0 = { (_Float16)a0[4 * g + 0], (_Float16)a0[4 * g + 1],
                              (_Float16)a0[4 * g + 2], (_Float16)a0[4 * g + 3] };
                *(half4v*)&S16[SWH(ncol, pc0 + 8 * g)] = h0;
                half4v h1 = { (_Float16)a1[4 * g + 0], (_Float16)a1[4 * g + 1],
                              (_Float16)a1[4 * g + 2], (_Float16)a1[4 * g + 3] };
                *(half4v*)&S16[SWH(ncol + 32, pc0 + 8 * g)] = h1;
            }
        }
        BAR_LGKM();   // S_in ready; all u32t reads complete (strip now dead)

        // issue DMA for seq+1 into the freed strip: covered by scan + GEMM2
        if (sq + 1 < NSEQ) {
            const float* ub = u + ((size_t)((bbg * NSEQ + sq + 1) * 256) + h) * 8192;
#pragma unroll
            for (int q = 0; q < 8; ++q) {
                int c = (wv << 4) + (q << 1) + (lane >> 5);
                int q4 = (lane & 31) ^ (c & 31);
                dma16(ub + (c << 7) + (q4 << 2), u32t + (((wv << 4) + (q << 1)) << 7));
            }
        }

        // ---- chunk-state scan: wave wv owns chunks [16wv, 16wv+16), in place ----
        const int cbase = wv << 4;
        float sr = 0.f, si = 0.f, pr = 1.f, pi = 0.f;
#pragma unroll
        for (int d = 0; d < 8; ++d) {   // 8-tap circular warm start (cross-wave reads)
            int cc = (cbase - 1 - d) & 63;
            half2v xv = *(const half2v*)&S16[SWH(cc, lane << 1)];
            float xr = (float)xv.x, xi = (float)xv.y;
            sr = fmaf(pr, xr, fmaf(-pi, xi, sr));
            si = fmaf(pr, xi, fmaf(pi, xr, si));
            float npr = pr * amr - pi * ami;
            float npi = pr * ami + pi * amr;
            pr = npr; pi = npi;
        }
        BAR_LGKM();   // all warm-up reads done before any in-place overwrite
#pragma unroll
        for (int i = 0; i < 16; ++i) {   // own rows: read S_in, write ENTERING state
            int c = cbase + i;
            half2v xv = *(const half2v*)&S16[SWH(c, lane << 1)];
            half2v ev = { (_Float16)sr, (_Float16)si };
            *(half2v*)&S16[SWH(c, lane << 1)] = ev;
            float xr = (float)xv.x, xi = (float)xv.y;
            float nr = fmaf(amr, sr, fmaf(-ami, si, xr));
            float ni = fmaf(amr, si, fmaf(ami, sr, xi));
            sr = nr; si = ni;
        }
        BAR_LGKM();   // sB ready

        // ---- GEMM2: y = G*sB + T'*u16, tanh + store ----
        {
            floatx16 y0 = {}; floatx16 y1 = {};
#pragma unroll
            for (int s = 0; s < 8; ++s) {          // G * sB
                int k0 = (s << 4) + kh;
                half8 b0 = *(const half8*)&S16[SWH(ncol, k0)];
                half8 b1 = *(const half8*)&S16[SWH(ncol + 32, k0)];
                y0 = __builtin_amdgcn_mfma_f32_32x32x16_f16(gf[s], b0, y0, 0, 0, 0);
                y1 = __builtin_amdgcn_mfma_f32_32x32x16_f16(gf[s], b1, y1, 0, 0, 0);
            }
#pragma unroll
            for (int s = 0; s < 8; ++s) {          // T' * u
                int k0 = (s << 4) + kh;
                half8 b0 = *(const half8*)&u16t[SWH(ncol, k0)];
                half8 b1 = *(const half8*)&u16t[SWH(ncol + 32, k0)];
                y0 = __builtin_amdgcn_mfma_f32_32x32x16_f16(tf[s], b0, y0, 0, 0, 0);
                y1 = __builtin_amdgcn_mfma_f32_32x32x16_f16(tf[s], b1, y1, 0, 0, 0);
            }
            float* yb = out + ((size_t)((bbg * NSEQ + sq) * 256) + h) * 8192;
            const int r0 = (wv << 5) + ((lane >> 5) << 2);
#pragma unroll
            for (int g = 0; g < 4; ++g) {
                float4 o0;
                o0.x = fast_tanh(y0[4 * g + 0]); o0.y = fast_tanh(y0[4 * g + 1]);
                o0.z = fast_tanh(y0[4 * g + 2]); o0.w = fast_tanh(y0[4 * g + 3]);
                *(float4*)(yb + (size_t)ncol * CM + r0 + 8 * g) = o0;
                float4 o1;
                o1.x = fast_tanh(y1[4 * g + 0]); o1.y = fast_tanh(y1[4 * g + 1]);
                o1.z = fast_tanh(y1[4 * g + 2]); o1.w = fast_tanh(y1[4 * g + 3]);
                *(float4*)(yb + (size_t)(ncol + 32) * CM + r0 + 8 * g) = o1;
            }
        }
        // full drain: next-seq DMA complete, stores retired, S16/u16 reuse safe
        __syncthreads();
    }
}

extern "C" void kernel_launch(void* const* d_in, const int* in_sizes, int n_in,
                              void* d_out, int out_size, void* d_ws, size_t ws_size,
                              hipStream_t stream) {
    const float* u     = (const float*)d_in[0];
    const float* A_re  = (const float*)d_in[1];
    const float* A_im  = (const float*)d_in[2];
    const float* BC_re = (const float*)d_in[3];
    const float* BC_im = (const float*)d_in[4];
    const float* Dv    = (const float*)d_in[5];
    float* out = (float*)d_out;
    char* ws = (char*)d_ws;

    hipLaunchKernelGGL(fftconv_prep, dim3(256), dim3(256), 0, stream,
                       A_re, A_im, BC_re, BC_im, Dv, ws);
    hipLaunchKernelGGL(fftconv_main, dim3(1024), dim3(256), 0, stream,
                       u, ws, out);
}